// Round 3
// baseline (217.352 us; speedup 1.0000x reference)
//
#include <hip/hip_runtime.h>
#include <math.h>

#define NBULK 62
#define SB    72   // padded LDS row stride (bf16) for norm-path E/St tiles

typedef __attribute__((ext_vector_type(8))) short bf8_t;    // 8 x bf16
typedef __attribute__((ext_vector_type(4))) float f4_t;     // 4 x fp32
typedef __attribute__((ext_vector_type(16))) float f16v_t;  // 16 x fp32

#define MFMA16(a, b, c) __builtin_amdgcn_mfma_f32_16x16x32_bf16((a), (b), (c), 0, 0, 0)
#define MFMA32(a, b, c) __builtin_amdgcn_mfma_f32_32x32x16_bf16((a), (b), (c), 0, 0, 0)

__device__ __forceinline__ unsigned short f2bf(float f) {
    unsigned int u = __float_as_uint(f);
    return (unsigned short)((u + 0x7FFFu + ((u >> 16) & 1u)) >> 16);
}
__device__ __forceinline__ float bf2f(unsigned short h) {
    return __uint_as_float(((unsigned int)h) << 16);
}
// pack 2 f32 -> 2 bf16 in one dword (RNE)
__device__ __forceinline__ unsigned cvtpk(float lo, float hi) {
    unsigned r;
    asm("v_cvt_pk_bf16_f32 %0, %1, %2" : "=v"(r) : "v"(lo), "v"(hi));
    return r;
}

// async global->LDS, 16B per lane; lptr must be wave-uniform (HW adds lane*16)
__device__ __forceinline__ void gload16(const void* g, void* l) {
    __builtin_amdgcn_global_load_lds(
        (const __attribute__((address_space(1))) unsigned int*)g,
        (__attribute__((address_space(3))) unsigned int*)l, 16, 0, 0);
}

// ---- ws layout ----
// floats: [0]=psisum [1]=lsf [2]=lsb [3]=done-counter(int) ; E_fwd @f1024, E_bwd @f6144
// bytes:  BT (swizzled, 62*16KB) @45056 ; MR (swizzled) @1060864 ; AF (frag-ordered) @2076672
#define WS_E_OFF   1024
#define WS_B_OFF   6144
#define WS_BT_OFF  45056
#define WS_MR_OFF  1060864
#define WS_AF_OFF  2076672

// BT/MR tiles: swizzled offset of (row n, col k) in a 128x64 bf16 tile:
//   n*64 + ((k>>3 ^ (n&7))<<3 | (k&7)); 8-contig k-group g at n*64 + ((g^(n&7))<<3)
// AF tiles (psi A-fragments, COALESCED): chunk q=(p*2+jt)*4+ks (1KB each); lane l=hi*32+s
// holds 8 bf16 at q*1024+l*16: A[row=jt*32+s][k=16ks+8*(d>>2)+4hi+(d&3)], d=0..7
// where A[row][k] = M_p[k][row] = bulk[t][k][p][row]  (kappa permutation baked in)

extern "C" __global__ __launch_bounds__(256)
void mps_precompute(const float* __restrict__ bulkG,
                    unsigned short* __restrict__ BTg,
                    unsigned short* __restrict__ MRg,
                    unsigned short* __restrict__ AFg,
                    float* __restrict__ wsF)
{
    __shared__ unsigned short BTl[8192];
    __shared__ unsigned short MRl[8192];
    __shared__ unsigned short AFl[8192];
    const int s = blockIdx.x, tid = threadIdx.x;
    if (s == 0 && tid == 0) {   // init accumulators + done-counter (no memset dispatch)
        wsF[0] = 0.f; wsF[1] = 0.f; wsF[2] = 0.f; wsF[3] = 0.f;
    }
    const float4* src = (const float4*)(bulkG + (size_t)s * 8192);
    for (int c = 0; c < 8; ++c) {
        int idx = tid + c * 256;            // 0..2047
        float4 v = src[idx];
        int f  = idx * 4;
        int kk = f >> 7;                    // 0..63
        int p  = (f >> 6) & 1;
        int j  = f & 63;                    // multiple of 4
        unsigned short b0 = f2bf(v.x), b1 = f2bf(v.y), b2 = f2bf(v.z), b3 = f2bf(v.w);
        unsigned short bb[4] = {b0, b1, b2, b3};
        // MR row n = p*64+kk holds M_p[kk][:]
        int n = p * 64 + kk;
        int off = n * 64 + (((j >> 3) ^ (n & 7)) << 3) + (j & 7);
        MRl[off + 0] = b0; MRl[off + 1] = b1; MRl[off + 2] = b2; MRl[off + 3] = b3;
        // BT rows n' = p*64 + j.. hold columns of M_p
        #pragma unroll
        for (int t2 = 0; t2 < 4; ++t2) {
            int n2 = p * 64 + j + t2;
            BTl[n2 * 64 + (((kk >> 3) ^ (n2 & 7)) << 3) + (kk & 7)] = bb[t2];
        }
        // AF: chunk q, lane hi*32+s2, halfword d  (psi fragment-ready)
        {
            int hi32 = (kk >> 2) & 1;
            int d    = 4 * ((kk >> 3) & 1) + (kk & 3);
            int q    = (p * 2 + (j >> 5)) * 4 + (kk >> 4);
            int base = q * 512 + (hi32 * 32 + (j & 31)) * 8 + d;
            #pragma unroll
            for (int t2 = 0; t2 < 4; ++t2)
                AFl[base + t2 * 8] = bb[t2];
        }
    }
    __syncthreads();
    const uint4* bt4 = (const uint4*)BTl;
    const uint4* mr4 = (const uint4*)MRl;
    const uint4* af4 = (const uint4*)AFl;
    uint4* btg = (uint4*)(BTg + (size_t)s * 8192);
    uint4* mrg = (uint4*)(MRg + (size_t)s * 8192);
    uint4* afg = (uint4*)(AFg + (size_t)s * 8192);
    for (int c = 0; c < 4; ++c) {
        int idx = tid + c * 256;
        btg[idx] = bt4[idx];
        mrg[idx] = mr4[idx];
        afg[idx] = af4[idx];
    }
}

// ===================== psi: fully in-register chain =====================
// One wave = 32 samples, zero LDS, zero barriers. env lives in MFMA B-fragments.
// B[ks] := cvtpk-packed C[jt=ks>>1] regs [8(ks&1)..8(ks&1)+7] (pure lane-local pack);
// the matching kappa k-permutation is baked into the AF global layout, so the
// A-fetch is 16 perfectly-coalesced 16B/lane loads (the round-2 regression was
// this fetch as a 128B-stride gather: ~32 cache lines per instruction).

__device__ __forceinline__ void psi_fetch(uint4 (&A)[16], const char* tb, int lane16)
{
    #pragma unroll
    for (int q = 0; q < 16; ++q)
        A[q] = *(const uint4*)(tb + q * 1024 + lane16);
}

__device__ __forceinline__ void psi_mfma(f16v_t (&c)[2][2], const uint4 (&A)[16],
                                         const bf8_t (&B)[4], const f16v_t& Z)
{
    #pragma unroll
    for (int p = 0; p < 2; ++p)
        #pragma unroll
        for (int jt = 0; jt < 2; ++jt)
            c[p][jt] = Z;
    #pragma unroll
    for (int ks = 0; ks < 4; ++ks)
        #pragma unroll
        for (int p = 0; p < 2; ++p)
            #pragma unroll
            for (int jt = 0; jt < 2; ++jt)
                c[p][jt] = MFMA32(*(const bf8_t*)&A[p * 8 + jt * 4 + ks], B[ks], c[p][jt]);
}

__device__ __forceinline__ void psi_pack(bf8_t (&B)[4], const f16v_t (&c)[2][2], bool takeB)
{
    #pragma unroll
    for (int ks = 0; ks < 4; ++ks) {
        const int jt = ks >> 1, h8 = (ks & 1) * 8;
        uint4 w;
        float x0, x1;
        x0 = takeB ? c[1][jt][h8 + 0] : c[0][jt][h8 + 0];
        x1 = takeB ? c[1][jt][h8 + 1] : c[0][jt][h8 + 1];
        w.x = cvtpk(x0, x1);
        x0 = takeB ? c[1][jt][h8 + 2] : c[0][jt][h8 + 2];
        x1 = takeB ? c[1][jt][h8 + 3] : c[0][jt][h8 + 3];
        w.y = cvtpk(x0, x1);
        x0 = takeB ? c[1][jt][h8 + 4] : c[0][jt][h8 + 4];
        x1 = takeB ? c[1][jt][h8 + 5] : c[0][jt][h8 + 5];
        w.z = cvtpk(x0, x1);
        x0 = takeB ? c[1][jt][h8 + 6] : c[0][jt][h8 + 6];
        x1 = takeB ? c[1][jt][h8 + 7] : c[0][jt][h8 + 7];
        w.w = cvtpk(x0, x1);
        B[ks] = *(const bf8_t*)&w;
    }
}

extern "C" __global__ __launch_bounds__(256, 1)
void mps_main(const int* __restrict__ cfgG, const float* __restrict__ leftG,
              const float* __restrict__ rightG, float* __restrict__ wsF,
              const unsigned short* __restrict__ BTg,
              const unsigned short* __restrict__ MRg,
              const unsigned short* __restrict__ AFg,
              float* __restrict__ outG)
{
    extern __shared__ char smem[];
    unsigned short* smem16 = (unsigned short*)smem;
    __shared__ int lastf;
    const int tid  = threadIdx.x;
    const int bid  = blockIdx.x;
    const int wv   = tid >> 6;
    const int lane = tid & 63;

    if (bid >= 2 && wv < 2) {
        // ========== psi: 64 samples/block; waves 0,1 = independent barrier-free
        // 32-sample in-register chains; waves 2,3 idle to the finalize barrier ==========
        const int s  = lane & 31;    // sample within wave (also A-row index)
        const int hi = lane >> 5;
        const int lane16 = lane * 16;
        const char* AFb = (const char*)AFg;

        uint4 Aa[16], Ab[16];
        psi_fetch(Aa, AFb, lane16);             // tile 0
        psi_fetch(Ab, AFb + 16384, lane16);     // tile 1

        // pack this lane's sample config into 2 dwords (bit j = cfg column j)
        const int s0 = (bid - 2) * 64 + wv * 32;
        unsigned mbits = 0;
        {
            const int4* crow = (const int4*)(cfgG + (size_t)(s0 + s) * 64 + hi * 32);
            #pragma unroll
            for (int c2 = 0; c2 < 8; ++c2) {
                int4 v = crow[c2];
                mbits |= (unsigned)(v.x & 1) << (c2 * 4 + 0);
                mbits |= (unsigned)(v.y & 1) << (c2 * 4 + 1);
                mbits |= (unsigned)(v.z & 1) << (c2 * 4 + 2);
                mbits |= (unsigned)(v.w & 1) << (c2 * 4 + 3);
            }
        }
        unsigned other = __shfl_xor(mbits, 32);
        unsigned selLo = hi ? other : mbits;   // cfg cols 0..31
        unsigned selHi = hi ? mbits : other;   // cfg cols 32..63

        // env0 = left[cfg[:,0]] directly into B-fragments (kappa gather)
        bf8_t B[4];
        {
            const float* lp = leftG + (selLo & 1u) * 64;
            #pragma unroll
            for (int ks = 0; ks < 4; ++ks) {
                uint4 w;
                unsigned wd[4];
                #pragma unroll
                for (int d = 0; d < 4; ++d) {
                    int k0 = 16 * ks + 8 * (d >> 1) + 2 * (d & 1) + 4 * hi;
                    wd[d] = (unsigned)f2bf(lp[k0]) | ((unsigned)f2bf(lp[k0 + 1]) << 16);
                }
                w.x = wd[0]; w.y = wd[1]; w.z = wd[2]; w.w = wd[3];
                B[ks] = *(const bf8_t*)&w;
            }
        }

        const f16v_t Z = {0.f};
        f16v_t c[2][2];
        #define SELBIT(i) ((bool)((((i) < 32) ? (selLo >> (i)) : (selHi >> ((i) - 32))) & 1u))
        for (int t = 0; t < 60; t += 2) {
            psi_mfma(c, Aa, B, Z);
            psi_fetch(Aa, AFb + (size_t)(t + 2) * 16384, lane16);   // consumed at t+2
            psi_pack(B, c, SELBIT(t + 1));
            psi_mfma(c, Ab, B, Z);
            psi_fetch(Ab, AFb + (size_t)(t + 3) * 16384, lane16);   // consumed at t+3
            psi_pack(B, c, SELBIT(t + 2));
        }
        psi_mfma(c, Aa, B, Z);        // step 60
        psi_pack(B, c, SELBIT(61));
        psi_mfma(c, Ab, B, Z);        // step 61
        {   // final select (cfg col 62) + dot with right[:, cfg col 63]
            const bool tb2 = SELBIT(62);
            const int selL = (int)(selHi >> 31) & 1;
            float psum = 0.f;
            #pragma unroll
            for (int jt = 0; jt < 2; ++jt)
                #pragma unroll
                for (int q = 0; q < 16; ++q) {
                    float v = tb2 ? c[1][jt][q] : c[0][jt][q];
                    int idx = 32 * jt + (q & 3) + 8 * (q >> 2) + 4 * hi;
                    psum = fmaf(v, rightG[idx * 2 + selL], psum);
                }
            psum += __shfl_xor(psum, 32);   // combine complementary halves
            float lp2 = logf(fmaxf(psum * psum, 1e-12f));
            if (hi) lp2 = 0.f;              // lanes l and l^32 hold the same sample
            #pragma unroll
            for (int o = 1; o < 64; o <<= 1) lp2 += __shfl_xor(lp2, o);
            if (lane == 0) atomicAdd(&wsF[0], lp2);
        }
        #undef SELBIT
    } else if (bid < 2) {
        // ========== norm chain: fwd (bid 0) / bwd (bid 1), 31 sites, deferred rescale ==========
        unsigned short* Ebf = smem16;                    // 64 x SB (E, symmetric)
        unsigned short* St0 = Ebf + 64 * SB;
        unsigned short* St1 = St0 + 64 * SB;
        unsigned short* Ms0 = St1 + 64 * SB;             // 8192 (swizzled tile)
        unsigned short* Ms1 = Ms0 + 8192;
        float* wred = (float*)(Ms1 + 8192);              // [2][4]

        const int quad = lane >> 4;
        const int ln   = lane & 15;
        const bool fwd = (bid == 0);
        const unsigned short* srcbase = fwd ? BTg : MRg;
        {   // E0
            int i = tid >> 2, jq = tid & 3;
            for (int jj = 0; jj < 16; ++jj) {
                int j = jq * 16 + jj;
                float v;
                if (fwd) v = leftG[i] * leftG[j] + leftG[64 + i] * leftG[64 + j];
                else     v = rightG[i * 2] * rightG[j * 2] + rightG[i * 2 + 1] * rightG[j * 2 + 1];
                Ebf[i * SB + j] = f2bf(v);
            }
        }
        {   // prefetch site 0
            int st = fwd ? 0 : 61;
            const char* g = (const char*)(srcbase + (size_t)st * 8192);
            for (int c = 0; c < 4; ++c) {
                int chunk = wv * 4 + c;
                gload16(g + chunk * 1024 + (size_t)lane * 16, (char*)Ms0 + chunk * 1024);
            }
        }
        float lsum = 0.f;
        const int p   = wv >> 1;
        const int ntb = (wv & 1) * 2;
        const int mta = (wv >> 1) * 2;
        const int nta = (wv & 1) * 2;
        unsigned short* Stp = p ? St1 : St0;

        for (int k = 0; k < 31; ++k) {
            __syncthreads();   // Ms[k&1] resident; Ebf(k-1), wred(k-1) visible
            unsigned short* M = (k & 1) ? Ms1 : Ms0;
            if (k + 1 < 31) {
                int sn = fwd ? (k + 1) : (61 - (k + 1));
                const char* g = (const char*)(srcbase + (size_t)sn * 8192);
                char* l = (char*)((k & 1) ? Ms0 : Ms1);
                for (int c = 0; c < 4; ++c) {
                    int chunk = wv * 4 + c;
                    gload16(g + chunk * 1024 + (size_t)lane * 16, l + chunk * 1024);
                }
            }
            float inv = 1.f;
            if (k > 0) {
                const float* wp = wred + ((k - 1) & 1) * 4;
                float mm = fmaxf(fmaxf(wp[0], wp[1]), fmaxf(wp[2], wp[3]));
                float sc = fmaxf(mm, 1e-30f);
                inv = 1.f / sc;
                if (tid == 0) lsum += logf(sc);
            }
            // stage1: S_p = E * Op_p  (St stores transposed)
            {
                bf8_t Af2[4][2];
                #pragma unroll
                for (int mt = 0; mt < 4; ++mt)
                    #pragma unroll
                    for (int h = 0; h < 2; ++h)
                        Af2[mt][h] = *(const bf8_t*)(Ebf + (mt * 16 + ln) * SB + h * 32 + quad * 8);
                #pragma unroll
                for (int c = 0; c < 2; ++c) {
                    int nt = ntb + c;
                    int row = p * 64 + nt * 16 + ln;
                    bf8_t B0 = *(const bf8_t*)(M + row * 64 + (((0 + quad) ^ (ln & 7)) << 3));
                    bf8_t B1 = *(const bf8_t*)(M + row * 64 + (((4 + quad) ^ (ln & 7)) << 3));
                    #pragma unroll
                    for (int mt = 0; mt < 4; ++mt) {
                        f4_t a = {0.f, 0.f, 0.f, 0.f};
                        a = MFMA16(Af2[mt][0], B0, a);
                        a = MFMA16(Af2[mt][1], B1, a);
                        ushort4 pk;
                        pk.x = f2bf(a[0]); pk.y = f2bf(a[1]); pk.z = f2bf(a[2]); pk.w = f2bf(a[3]);
                        *(ushort4*)(Stp + (nt * 16 + ln) * SB + mt * 16 + quad * 4) = pk;
                    }
                }
            }
            __syncthreads();   // St ready; stage1 Ebf reads done
            // stage2: E' = sum_p Op_p-side * S_p ; scale by prev-site max; write Ebf
            {
                bf8_t Aw[2][2][2], Bw[2][2][2];
                #pragma unroll
                for (int pp = 0; pp < 2; ++pp)
                    #pragma unroll
                    for (int mi = 0; mi < 2; ++mi)
                        #pragma unroll
                        for (int h = 0; h < 2; ++h)
                            Aw[pp][mi][h] = *(const bf8_t*)(M + (pp * 64 + (mta + mi) * 16 + ln) * 64
                                                              + (((h * 4 + quad) ^ (ln & 7)) << 3));
                #pragma unroll
                for (int pp = 0; pp < 2; ++pp)
                    #pragma unroll
                    for (int ni = 0; ni < 2; ++ni)
                        #pragma unroll
                        for (int h = 0; h < 2; ++h)
                            Bw[pp][ni][h] = *(const bf8_t*)((pp ? St1 : St0)
                                                            + ((nta + ni) * 16 + ln) * SB + h * 32 + quad * 8);
                float mx = 0.f;
                #pragma unroll
                for (int mi = 0; mi < 2; ++mi)
                    #pragma unroll
                    for (int ni = 0; ni < 2; ++ni) {
                        f4_t a = {0.f, 0.f, 0.f, 0.f};
                        #pragma unroll
                        for (int pp = 0; pp < 2; ++pp)
                            #pragma unroll
                            for (int h = 0; h < 2; ++h)
                                a = MFMA16(Aw[pp][mi][h], Bw[pp][ni][h], a);
                        // E' symmetric -> write transposed element: one b64 store
                        float x0 = a[0] * inv, x1 = a[1] * inv, x2 = a[2] * inv, x3 = a[3] * inv;
                        mx = fmaxf(mx, fmaxf(fmaxf(fabsf(x0), fabsf(x1)), fmaxf(fabsf(x2), fabsf(x3))));
                        ushort4 pk;
                        pk.x = f2bf(x0); pk.y = f2bf(x1); pk.z = f2bf(x2); pk.w = f2bf(x3);
                        *(ushort4*)(Ebf + ((nta + ni) * 16 + ln) * SB + (mta + mi) * 16 + quad * 4) = pk;
                    }
                #pragma unroll
                for (int off2 = 32; off2 > 0; off2 >>= 1)
                    mx = fmaxf(mx, __shfl_xor(mx, off2));
                if (lane == 0) wred[(k & 1) * 4 + wv] = mx;
            }
        }
        __syncthreads();
        float* dst = wsF + (fwd ? WS_E_OFF : WS_B_OFF);
        for (int c = 0; c < 16; ++c) {
            int idx = tid + c * 256;
            dst[idx] = bf2f(Ebf[(idx >> 6) * SB + (idx & 63)]);
        }
        if (tid == 0) wsF[fwd ? 1 : 2] = lsum;
    }

    // ========== merged finalize: last block to finish runs it ==========
    __threadfence();
    if (tid == 0)
        lastf = (atomicAdd((int*)&wsF[3], 1) == (int)gridDim.x - 1);
    __syncthreads();
    if (lastf) {
        __threadfence();   // acquire: see all other blocks' writes
        if (wv == 0) {
            const float* E  = wsF + WS_E_OFF;
            const float* Bm = wsF + WS_B_OFF;
            float a = 0.f;
            #pragma unroll 8
            for (int c2 = 0; c2 < 64; ++c2)
                a = fmaf(E[c2 * 64 + lane], Bm[c2 * 64 + lane], a);   // coalesced
            #pragma unroll
            for (int o = 32; o > 0; o >>= 1)
                a += __shfl_down(a, o);
            if (lane == 0) {
                const float z = fmaxf(a, 1e-30f);
                const float log_z = logf(z) + wsF[1] + wsF[2];
                outG[0] = log_z - wsF[0] * (1.0f / 8192.0f);
            }
        }
    }
}

extern "C" void kernel_launch(void* const* d_in, const int* in_sizes, int n_in,
                              void* d_out, int out_size, void* d_ws, size_t ws_size,
                              hipStream_t stream)
{
    const int*   cfg   = (const int*)d_in[0];    // (8192, 64) int32
    const float* left  = (const float*)d_in[1];  // (2, 64)
    const float* bulk  = (const float*)d_in[2];  // (62, 64, 2, 64)
    const float* right = (const float*)d_in[3];  // (64, 2)
    float* wsF = (float*)d_ws;
    unsigned short* BTg = (unsigned short*)((char*)d_ws + WS_BT_OFF);
    unsigned short* MRg = (unsigned short*)((char*)d_ws + WS_MR_OFF);
    unsigned short* AFg = (unsigned short*)((char*)d_ws + WS_AF_OFF);

    mps_precompute<<<dim3(62), dim3(256), 0, stream>>>(bulk, BTg, MRg, AFg, wsF);
    // blocks 0,1 = norm chains; 2..129 = psi (64 samples each, 2 in-register waves)
    mps_main<<<dim3(130), dim3(256), 60480, stream>>>(cfg, left, right, wsF, BTg, MRg,
                                                      AFg, (float*)d_out);
}

// Round 4
// 150.444 us; speedup vs baseline: 1.4447x; 1.4447x over previous
//
#include <hip/hip_runtime.h>
#include <math.h>

#define NBULK 62
#define SB    72   // padded LDS row stride (bf16) for norm-path E/St tiles

typedef __attribute__((ext_vector_type(8))) short bf8_t;    // 8 x bf16
typedef __attribute__((ext_vector_type(4))) float f4_t;     // 4 x fp32
typedef __attribute__((ext_vector_type(16))) float f16v_t;  // 16 x fp32

#define MFMA16(a, b, c) __builtin_amdgcn_mfma_f32_16x16x32_bf16((a), (b), (c), 0, 0, 0)
#define MFMA32(a, b, c) __builtin_amdgcn_mfma_f32_32x32x16_bf16((a), (b), (c), 0, 0, 0)

__device__ __forceinline__ unsigned short f2bf(float f) {
    unsigned int u = __float_as_uint(f);
    return (unsigned short)((u + 0x7FFFu + ((u >> 16) & 1u)) >> 16);
}
__device__ __forceinline__ float bf2f(unsigned short h) {
    return __uint_as_float(((unsigned int)h) << 16);
}
// pack 2 f32 -> 2 bf16 in one dword (RNE)
__device__ __forceinline__ unsigned cvtpk(float lo, float hi) {
    unsigned r;
    asm("v_cvt_pk_bf16_f32 %0, %1, %2" : "=v"(r) : "v"(lo), "v"(hi));
    return r;
}

// async global->LDS, 16B per lane; lptr must be wave-uniform (HW adds lane*16)
__device__ __forceinline__ void gload16(const void* g, void* l) {
    __builtin_amdgcn_global_load_lds(
        (const __attribute__((address_space(1))) unsigned int*)g,
        (__attribute__((address_space(3))) unsigned int*)l, 16, 0, 0);
}

// ---- ws layout ----
// floats: [0]=psisum [1]=lsf [2]=lsb [3]=spare ; E_fwd @f1024, E_bwd @f6144
// bytes:  BT (swizzled, 62*16KB) @45056 ; MR (swizzled) @1060864 ; AF (frag-ordered) @2076672
#define WS_E_OFF   1024
#define WS_B_OFF   6144
#define WS_BT_OFF  45056
#define WS_MR_OFF  1060864
#define WS_AF_OFF  2076672

// BT/MR tiles: swizzled offset of (row n, col k) in a 128x64 bf16 tile:
//   n*64 + ((k>>3 ^ (n&7))<<3 | (k&7)); 8-contig k-group g at n*64 + ((g^(n&7))<<3)
// AF tiles (psi A-fragments, COALESCED): chunk q=(p*2+jt)*4+ks (1KB each); lane l
// holds 8 bf16 at q*1024+l*16 (kappa permutation baked in; see psi comment below)

extern "C" __global__ __launch_bounds__(256)
void mps_precompute(const float* __restrict__ bulkG,
                    unsigned short* __restrict__ BTg,
                    unsigned short* __restrict__ MRg,
                    unsigned short* __restrict__ AFg,
                    float* __restrict__ wsF)
{
    __shared__ unsigned short BTl[8192];
    __shared__ unsigned short MRl[8192];
    __shared__ unsigned short AFl[8192];
    const int s = blockIdx.x, tid = threadIdx.x;
    if (s == 0 && tid == 0) {   // init accumulators (no memset dispatch)
        wsF[0] = 0.f; wsF[1] = 0.f; wsF[2] = 0.f; wsF[3] = 0.f;
    }
    const float4* src = (const float4*)(bulkG + (size_t)s * 8192);
    for (int c = 0; c < 8; ++c) {
        int idx = tid + c * 256;            // 0..2047
        float4 v = src[idx];
        int f  = idx * 4;
        int kk = f >> 7;                    // 0..63
        int p  = (f >> 6) & 1;
        int j  = f & 63;                    // multiple of 4
        unsigned short b0 = f2bf(v.x), b1 = f2bf(v.y), b2 = f2bf(v.z), b3 = f2bf(v.w);
        unsigned short bb[4] = {b0, b1, b2, b3};
        // MR row n = p*64+kk holds M_p[kk][:]
        int n = p * 64 + kk;
        int off = n * 64 + (((j >> 3) ^ (n & 7)) << 3) + (j & 7);
        MRl[off + 0] = b0; MRl[off + 1] = b1; MRl[off + 2] = b2; MRl[off + 3] = b3;
        // BT rows n' = p*64 + j.. hold columns of M_p
        #pragma unroll
        for (int t2 = 0; t2 < 4; ++t2) {
            int n2 = p * 64 + j + t2;
            BTl[n2 * 64 + (((kk >> 3) ^ (n2 & 7)) << 3) + (kk & 7)] = bb[t2];
        }
        // AF: chunk q, lane hi*32+row, halfword d  (psi fragment-ready)
        {
            int hi32 = (kk >> 2) & 1;
            int d    = 4 * ((kk >> 3) & 1) + (kk & 3);
            int q    = (p * 2 + (j >> 5)) * 4 + (kk >> 4);
            int base = q * 512 + (hi32 * 32 + (j & 31)) * 8 + d;
            #pragma unroll
            for (int t2 = 0; t2 < 4; ++t2)
                AFl[base + t2 * 8] = bb[t2];
        }
    }
    __syncthreads();
    const uint4* bt4 = (const uint4*)BTl;
    const uint4* mr4 = (const uint4*)MRl;
    const uint4* af4 = (const uint4*)AFl;
    uint4* btg = (uint4*)(BTg + (size_t)s * 8192);
    uint4* mrg = (uint4*)(MRg + (size_t)s * 8192);
    uint4* afg = (uint4*)(AFg + (size_t)s * 8192);
    for (int c = 0; c < 4; ++c) {
        int idx = tid + c * 256;
        btg[idx] = bt4[idx];
        mrg[idx] = mr4[idx];
        afg[idx] = af4[idx];
    }
}

// ===================== psi: in-register chain, 2 chains per wave =====================
// Each wave runs TWO independent 32-sample chains that SHARE the A-tiles (site
// matrices) in registers; only B-fragments and accumulators are duplicated. The
// interleaved MFMA/pack streams of the two chains hide each other's dependent
// latency (round-3 ran one chain/wave at 1 wave/SIMD: zero latency hiding).
// B[ks] := cvtpk-packed C[jt=ks>>1] regs [8(ks&1)..8(ks&1)+7] (lane-local pack);
// the matching kappa k-permutation is baked into the AF layout (coalesced fetch).

__device__ __forceinline__ void psi_fetch(uint4 (&A)[16], const char* tb, int lane16)
{
    #pragma unroll
    for (int q = 0; q < 16; ++q)
        A[q] = *(const uint4*)(tb + q * 1024 + lane16);
}

__device__ __forceinline__ void psi_mfma2(f16v_t (&c0)[2][2], f16v_t (&c1)[2][2],
                                          const uint4 (&A)[16],
                                          const bf8_t (&B0)[4], const bf8_t (&B1)[4],
                                          const f16v_t& Z)
{
    #pragma unroll
    for (int p = 0; p < 2; ++p)
        #pragma unroll
        for (int jt = 0; jt < 2; ++jt) {
            c0[p][jt] = Z;
            c1[p][jt] = Z;
        }
    #pragma unroll
    for (int ks = 0; ks < 4; ++ks)
        #pragma unroll
        for (int p = 0; p < 2; ++p)
            #pragma unroll
            for (int jt = 0; jt < 2; ++jt) {
                const bf8_t a = *(const bf8_t*)&A[p * 8 + jt * 4 + ks];
                c0[p][jt] = MFMA32(a, B0[ks], c0[p][jt]);   // two independent
                c1[p][jt] = MFMA32(a, B1[ks], c1[p][jt]);   // MFMA streams
            }
}

__device__ __forceinline__ void psi_pack(bf8_t (&B)[4], const f16v_t (&c)[2][2], bool takeB)
{
    #pragma unroll
    for (int ks = 0; ks < 4; ++ks) {
        const int jt = ks >> 1, h8 = (ks & 1) * 8;
        uint4 w;
        float x0, x1;
        x0 = takeB ? c[1][jt][h8 + 0] : c[0][jt][h8 + 0];
        x1 = takeB ? c[1][jt][h8 + 1] : c[0][jt][h8 + 1];
        w.x = cvtpk(x0, x1);
        x0 = takeB ? c[1][jt][h8 + 2] : c[0][jt][h8 + 2];
        x1 = takeB ? c[1][jt][h8 + 3] : c[0][jt][h8 + 3];
        w.y = cvtpk(x0, x1);
        x0 = takeB ? c[1][jt][h8 + 4] : c[0][jt][h8 + 4];
        x1 = takeB ? c[1][jt][h8 + 5] : c[0][jt][h8 + 5];
        w.z = cvtpk(x0, x1);
        x0 = takeB ? c[1][jt][h8 + 6] : c[0][jt][h8 + 6];
        x1 = takeB ? c[1][jt][h8 + 7] : c[0][jt][h8 + 7];
        w.w = cvtpk(x0, x1);
        B[ks] = *(const bf8_t*)&w;
    }
}

// env0 = left[cfg[:,0]] directly into B-fragments (kappa gather)
__device__ __forceinline__ void psi_env0(bf8_t (&B)[4], const float* lp, int hi)
{
    #pragma unroll
    for (int ks = 0; ks < 4; ++ks) {
        uint4 w;
        unsigned wd[4];
        #pragma unroll
        for (int d = 0; d < 4; ++d) {
            int k0 = 16 * ks + 8 * (d >> 1) + 2 * (d & 1) + 4 * hi;
            wd[d] = (unsigned)f2bf(lp[k0]) | ((unsigned)f2bf(lp[k0 + 1]) << 16);
        }
        w.x = wd[0]; w.y = wd[1]; w.z = wd[2]; w.w = wd[3];
        B[ks] = *(const bf8_t*)&w;
    }
}

__device__ __forceinline__ unsigned psi_cfgbits(const int* cfgG, int sample, int hi)
{
    unsigned mbits = 0;
    const int4* crow = (const int4*)(cfgG + (size_t)sample * 64 + hi * 32);
    #pragma unroll
    for (int c2 = 0; c2 < 8; ++c2) {
        int4 v = crow[c2];
        mbits |= (unsigned)(v.x & 1) << (c2 * 4 + 0);
        mbits |= (unsigned)(v.y & 1) << (c2 * 4 + 1);
        mbits |= (unsigned)(v.z & 1) << (c2 * 4 + 2);
        mbits |= (unsigned)(v.w & 1) << (c2 * 4 + 3);
    }
    return mbits;
}

__device__ __forceinline__ float psi_final(const f16v_t (&c)[2][2], bool tb2,
                                           const float* rightG, int selL, int hi)
{
    float psum = 0.f;
    #pragma unroll
    for (int jt = 0; jt < 2; ++jt)
        #pragma unroll
        for (int q = 0; q < 16; ++q) {
            float v = tb2 ? c[1][jt][q] : c[0][jt][q];
            int idx = 32 * jt + (q & 3) + 8 * (q >> 2) + 4 * hi;
            psum = fmaf(v, rightG[idx * 2 + selL], psum);
        }
    psum += __shfl_xor(psum, 32);   // combine complementary k-halves
    return psum;
}

extern "C" __global__ __launch_bounds__(256, 1)
void mps_main(const int* __restrict__ cfgG, const float* __restrict__ leftG,
              const float* __restrict__ rightG, float* __restrict__ wsF,
              const unsigned short* __restrict__ BTg,
              const unsigned short* __restrict__ MRg,
              const unsigned short* __restrict__ AFg)
{
    extern __shared__ char smem[];
    unsigned short* smem16 = (unsigned short*)smem;
    const int tid  = threadIdx.x;
    const int bid  = blockIdx.x;
    const int wv   = tid >> 6;
    const int lane = tid & 63;

    if (bid >= 2) {
        // ========== psi: 256 samples/block; 4 waves x 2 chains x 32 samples ==========
        const int s  = lane & 31;    // sample-column within chain
        const int hi = lane >> 5;
        const int lane16 = lane * 16;
        const char* AFb = (const char*)AFg;

        uint4 Aa[16], Ab[16];
        psi_fetch(Aa, AFb, lane16);             // tile 0
        psi_fetch(Ab, AFb + 16384, lane16);     // tile 1

        const int s0 = (bid - 2) * 256 + wv * 64;   // chain0: s0+s ; chain1: s0+32+s
        unsigned m0 = psi_cfgbits(cfgG, s0 + s, hi);
        unsigned m1 = psi_cfgbits(cfgG, s0 + 32 + s, hi);
        unsigned o0 = __shfl_xor(m0, 32);
        unsigned o1 = __shfl_xor(m1, 32);
        const unsigned sl0 = hi ? o0 : m0, sh0 = hi ? m0 : o0;
        const unsigned sl1 = hi ? o1 : m1, sh1 = hi ? m1 : o1;

        bf8_t B0[4], B1[4];
        psi_env0(B0, leftG + (sl0 & 1u) * 64, hi);
        psi_env0(B1, leftG + (sl1 & 1u) * 64, hi);

        const f16v_t Z = {0.f};
        f16v_t c0[2][2], c1[2][2];
        #define SB0(i) ((bool)((((i) < 32) ? (sl0 >> (i)) : (sh0 >> ((i) - 32))) & 1u))
        #define SB1(i) ((bool)((((i) < 32) ? (sl1 >> (i)) : (sh1 >> ((i) - 32))) & 1u))
        for (int t = 0; t < 60; t += 2) {
            psi_mfma2(c0, c1, Aa, B0, B1, Z);
            psi_fetch(Aa, AFb + (size_t)(t + 2) * 16384, lane16);   // consumed at t+2
            psi_pack(B0, c0, SB0(t + 1));
            psi_pack(B1, c1, SB1(t + 1));
            psi_mfma2(c0, c1, Ab, B0, B1, Z);
            psi_fetch(Ab, AFb + (size_t)(t + 3) * 16384, lane16);   // consumed at t+3
            psi_pack(B0, c0, SB0(t + 2));
            psi_pack(B1, c1, SB1(t + 2));
        }
        psi_mfma2(c0, c1, Aa, B0, B1, Z);   // step 60
        psi_pack(B0, c0, SB0(61));
        psi_pack(B1, c1, SB1(61));
        psi_mfma2(c0, c1, Ab, B0, B1, Z);   // step 61
        {   // final select (cfg col 62) + dot with right[:, cfg col 63]
            float p0 = psi_final(c0, SB0(62), rightG, (int)(sh0 >> 31) & 1, hi);
            float p1 = psi_final(c1, SB1(62), rightG, (int)(sh1 >> 31) & 1, hi);
            float lp2 = logf(fmaxf(p0 * p0, 1e-12f)) + logf(fmaxf(p1 * p1, 1e-12f));
            if (hi) lp2 = 0.f;              // lanes l and l^32 hold the same samples
            #pragma unroll
            for (int o = 1; o < 64; o <<= 1) lp2 += __shfl_xor(lp2, o);
            if (lane == 0) atomicAdd(&wsF[0], lp2);
        }
        #undef SB0
        #undef SB1
    } else {
        // ========== norm chain: fwd (bid 0) / bwd (bid 1), 31 sites, deferred rescale ==========
        unsigned short* Ebf = smem16;                    // 64 x SB (E, symmetric)
        unsigned short* St0 = Ebf + 64 * SB;
        unsigned short* St1 = St0 + 64 * SB;
        unsigned short* Ms0 = St1 + 64 * SB;             // 8192 (swizzled tile)
        unsigned short* Ms1 = Ms0 + 8192;
        float* wred = (float*)(Ms1 + 8192);              // [2][4]

        const int quad = lane >> 4;
        const int ln   = lane & 15;
        const bool fwd = (bid == 0);
        const unsigned short* srcbase = fwd ? BTg : MRg;
        {   // E0
            int i = tid >> 2, jq = tid & 3;
            for (int jj = 0; jj < 16; ++jj) {
                int j = jq * 16 + jj;
                float v;
                if (fwd) v = leftG[i] * leftG[j] + leftG[64 + i] * leftG[64 + j];
                else     v = rightG[i * 2] * rightG[j * 2] + rightG[i * 2 + 1] * rightG[j * 2 + 1];
                Ebf[i * SB + j] = f2bf(v);
            }
        }
        {   // prefetch site 0
            int st = fwd ? 0 : 61;
            const char* g = (const char*)(srcbase + (size_t)st * 8192);
            for (int c = 0; c < 4; ++c) {
                int chunk = wv * 4 + c;
                gload16(g + chunk * 1024 + (size_t)lane * 16, (char*)Ms0 + chunk * 1024);
            }
        }
        float lsum = 0.f;
        const int p   = wv >> 1;
        const int ntb = (wv & 1) * 2;
        const int mta = (wv >> 1) * 2;
        const int nta = (wv & 1) * 2;
        unsigned short* Stp = p ? St1 : St0;

        for (int k = 0; k < 31; ++k) {
            __syncthreads();   // Ms[k&1] resident; Ebf(k-1), wred(k-1) visible
            unsigned short* M = (k & 1) ? Ms1 : Ms0;
            if (k + 1 < 31) {
                int sn = fwd ? (k + 1) : (61 - (k + 1));
                const char* g = (const char*)(srcbase + (size_t)sn * 8192);
                char* l = (char*)((k & 1) ? Ms0 : Ms1);
                for (int c = 0; c < 4; ++c) {
                    int chunk = wv * 4 + c;
                    gload16(g + chunk * 1024 + (size_t)lane * 16, l + chunk * 1024);
                }
            }
            float inv = 1.f;
            if (k > 0) {
                const float* wp = wred + ((k - 1) & 1) * 4;
                float mm = fmaxf(fmaxf(wp[0], wp[1]), fmaxf(wp[2], wp[3]));
                float sc = fmaxf(mm, 1e-30f);
                inv = 1.f / sc;
                if (tid == 0) lsum += logf(sc);
            }
            // stage1: S_p = E * Op_p  (St stores transposed)
            {
                bf8_t Af2[4][2];
                #pragma unroll
                for (int mt = 0; mt < 4; ++mt)
                    #pragma unroll
                    for (int h = 0; h < 2; ++h)
                        Af2[mt][h] = *(const bf8_t*)(Ebf + (mt * 16 + ln) * SB + h * 32 + quad * 8);
                #pragma unroll
                for (int c = 0; c < 2; ++c) {
                    int nt = ntb + c;
                    int row = p * 64 + nt * 16 + ln;
                    bf8_t B0 = *(const bf8_t*)(M + row * 64 + (((0 + quad) ^ (ln & 7)) << 3));
                    bf8_t B1 = *(const bf8_t*)(M + row * 64 + (((4 + quad) ^ (ln & 7)) << 3));
                    #pragma unroll
                    for (int mt = 0; mt < 4; ++mt) {
                        f4_t a = {0.f, 0.f, 0.f, 0.f};
                        a = MFMA16(Af2[mt][0], B0, a);
                        a = MFMA16(Af2[mt][1], B1, a);
                        ushort4 pk;
                        pk.x = f2bf(a[0]); pk.y = f2bf(a[1]); pk.z = f2bf(a[2]); pk.w = f2bf(a[3]);
                        *(ushort4*)(Stp + (nt * 16 + ln) * SB + mt * 16 + quad * 4) = pk;
                    }
                }
            }
            __syncthreads();   // St ready; stage1 Ebf reads done
            // stage2: E' = sum_p Op_p-side * S_p ; scale by prev-site max; write Ebf
            {
                bf8_t Aw[2][2][2], Bw[2][2][2];
                #pragma unroll
                for (int pp = 0; pp < 2; ++pp)
                    #pragma unroll
                    for (int mi = 0; mi < 2; ++mi)
                        #pragma unroll
                        for (int h = 0; h < 2; ++h)
                            Aw[pp][mi][h] = *(const bf8_t*)(M + (pp * 64 + (mta + mi) * 16 + ln) * 64
                                                              + (((h * 4 + quad) ^ (ln & 7)) << 3));
                #pragma unroll
                for (int pp = 0; pp < 2; ++pp)
                    #pragma unroll
                    for (int ni = 0; ni < 2; ++ni)
                        #pragma unroll
                        for (int h = 0; h < 2; ++h)
                            Bw[pp][ni][h] = *(const bf8_t*)((pp ? St1 : St0)
                                                            + ((nta + ni) * 16 + ln) * SB + h * 32 + quad * 8);
                float mx = 0.f;
                #pragma unroll
                for (int mi = 0; mi < 2; ++mi)
                    #pragma unroll
                    for (int ni = 0; ni < 2; ++ni) {
                        f4_t a = {0.f, 0.f, 0.f, 0.f};
                        #pragma unroll
                        for (int pp = 0; pp < 2; ++pp)
                            #pragma unroll
                            for (int h = 0; h < 2; ++h)
                                a = MFMA16(Aw[pp][mi][h], Bw[pp][ni][h], a);
                        // E' symmetric -> write transposed element: one b64 store
                        float x0 = a[0] * inv, x1 = a[1] * inv, x2 = a[2] * inv, x3 = a[3] * inv;
                        mx = fmaxf(mx, fmaxf(fmaxf(fabsf(x0), fabsf(x1)), fmaxf(fabsf(x2), fabsf(x3))));
                        ushort4 pk;
                        pk.x = f2bf(x0); pk.y = f2bf(x1); pk.z = f2bf(x2); pk.w = f2bf(x3);
                        *(ushort4*)(Ebf + ((nta + ni) * 16 + ln) * SB + (mta + mi) * 16 + quad * 4) = pk;
                    }
                #pragma unroll
                for (int off2 = 32; off2 > 0; off2 >>= 1)
                    mx = fmaxf(mx, __shfl_xor(mx, off2));
                if (lane == 0) wred[(k & 1) * 4 + wv] = mx;
            }
        }
        __syncthreads();
        float* dst = wsF + (fwd ? WS_E_OFF : WS_B_OFF);
        for (int c = 0; c < 16; ++c) {
            int idx = tid + c * 256;
            dst[idx] = bf2f(Ebf[(idx >> 6) * SB + (idx & 63)]);
        }
        if (tid == 0) wsF[fwd ? 1 : 2] = lsum;
    }
}

extern "C" __global__ void mps_finalize(const float* __restrict__ wsF, float* __restrict__ out)
{
    const int lane = threadIdx.x;  // 64 threads
    const float* E  = wsF + WS_E_OFF;
    const float* Bm = wsF + WS_B_OFF;
    float a = 0.f;
    #pragma unroll 8
    for (int j = 0; j < 64; ++j)
        a = fmaf(E[j * 64 + lane], Bm[j * 64 + lane], a);   // coalesced
    #pragma unroll
    for (int off = 32; off > 0; off >>= 1)
        a += __shfl_down(a, off);
    if (lane == 0) {
        const float z = fmaxf(a, 1e-30f);
        const float log_z = logf(z) + wsF[1] + wsF[2];
        out[0] = log_z - wsF[0] * (1.0f / 8192.0f);
    }
}

extern "C" void kernel_launch(void* const* d_in, const int* in_sizes, int n_in,
                              void* d_out, int out_size, void* d_ws, size_t ws_size,
                              hipStream_t stream)
{
    const int*   cfg   = (const int*)d_in[0];    // (8192, 64) int32
    const float* left  = (const float*)d_in[1];  // (2, 64)
    const float* bulk  = (const float*)d_in[2];  // (62, 64, 2, 64)
    const float* right = (const float*)d_in[3];  // (64, 2)
    float* wsF = (float*)d_ws;
    unsigned short* BTg = (unsigned short*)((char*)d_ws + WS_BT_OFF);
    unsigned short* MRg = (unsigned short*)((char*)d_ws + WS_MR_OFF);
    unsigned short* AFg = (unsigned short*)((char*)d_ws + WS_AF_OFF);

    mps_precompute<<<dim3(62), dim3(256), 0, stream>>>(bulk, BTg, MRg, AFg, wsF);
    // blocks 0,1 = norm chains; 2..33 = psi (256 samples each: 4 waves x 2 chains x 32)
    mps_main<<<dim3(34), dim3(256), 60480, stream>>>(cfg, left, right, wsF, BTg, MRg, AFg);
    mps_finalize<<<dim3(1), dim3(64), 0, stream>>>(wsF, (float*)d_out);
}